// Round 8
// baseline (445.177 us; speedup 1.0000x reference)
//
#include <hip/hip_runtime.h>
#include <hip/hip_bf16.h>

typedef unsigned short u16;
typedef __attribute__((ext_vector_type(8))) short bf16x8;    // 8 bf16 in 4 VGPRs
typedef __attribute__((ext_vector_type(4))) float f32x4;

static __device__ __forceinline__ u16 f2bf(float f) {
    unsigned u = __float_as_uint(f);
    unsigned r = (u + 0x7fffu + ((u >> 16) & 1u)) >> 16;   // RNE
    return (u16)r;
}
static __device__ __forceinline__ float bf2f(u16 u) {
    return __uint_as_float(((unsigned)u) << 16);
}

static __device__ __forceinline__ void async_copy16(const void* gptr, void* lptr) {
    __builtin_amdgcn_global_load_lds(
        (const __attribute__((address_space(1))) void*)gptr,
        (__attribute__((address_space(3))) void*)lptr, 16, 0, 0);
}

// ---------------------------------------------------------------------------
// fp32 -> bf16 for all three inputs, grid-stride (4096 blocks x 8 iters).
// Unit = float4. hs: 4,194,304 units; Win: 3,145,728; Wout: 1,048,576.
// ---------------------------------------------------------------------------
__global__ __launch_bounds__(256)
void cvt_all(const float* __restrict__ a, const float* __restrict__ b,
             const float* __restrict__ c,
             u16* __restrict__ oa, u16* __restrict__ ob, u16* __restrict__ oc) {
#pragma unroll
    for (int it = 0; it < 8; it++) {
        long li = ((long)it << 20) + (long)blockIdx.x * 256 + threadIdx.x;
        const float* src; u16* dst; long u;
        if (li < 4194304)      { src = a; dst = oa; u = li; }
        else if (li < 7340032) { src = b; dst = ob; u = li - 4194304; }
        else                   { src = c; dst = oc; u = li - 7340032; }
        long i = u * 4;
        float4 f = *(const float4*)(src + i);
        u16 o[4] = { f2bf(f.x), f2bf(f.y), f2bf(f.z), f2bf(f.w) };
        *(uint2*)(dst + i) = *(const uint2*)o;
    }
}

// ---------------------------------------------------------------------------
// C[m,n] = sum_k A[m,k] * B[n,k]   (row-major, K contiguous — "BT" gemm)
//
// 256x256 tile, BK=64, 512 threads = 8 waves (2M x 4N), wave tile 128x64 as
// 8x4 frags of mfma_f32_16x16x32_bf16 (16-row fragment reads = measured ZERO
// bank conflicts; 32-row variants measured 1.9e7).
//
// R8: PERSISTENT blocks (grid 256 = 1/CU). Block b -> XCD group (b&7) owns
// output columns [xcd*TPB, (xcd+1)*TPB), row slot b>>3; TPB = (N/256)/8
// (gemm1: 3, gemm2: 1). Per-XCD working set = TPB B-panels (1MB each) +
// 1 A-row-panel (1MB) -> L2-resident. A-sources are CONSTANT per block
// (tiles share the row); only B-sources re-derive per output tile.
//
// K-tile = 4 phases, 1 barrier each (R6 skeleton, best measured), with ONE
// DMA sync/tile: stages bunched ph1 (A0',B0') + ph2 (B1',A1'), single VM(0)
// at ph4-start (copies >=2 phases (~2200cy) old -> free). WAR audit: every
// stage target last read >= 3 barriers earlier; RAW: VM(0)+BAR@ph4 precedes
// all next-tile reads. lgkm counted per-phase (FIFO order pinned by SB()).
//
// Output-tile transition: the last K-tile's stage (formerly junk) stages the
// NEXT output tile's k=0 data (B-sources swapped just before it). After its
// ph4 VM(0)+BAR, the epilogue (register-only) runs, then the next K-loop
// starts directly — no extra barrier, transitions cost only the store issue.
//
// LDS (2 dbufs x 32768 u16): A-Mq at Mq*8192, B-Nq at 16384+Nq*8192;
// 16B slot s = kc ^ (rowslot&7). Swizzle pre-applied on the GLOBAL source
// (global_load_lds needs linear lane*16B dests); reads un-swizzle with the
// same XOR. (R1-verbatim zero-conflict geometry.)
// Requires: M == 8192 (32 row slots), N/256 % 8 == 0, K mult of 128, K>=256.
// ---------------------------------------------------------------------------
template<bool BF16_OUT>
__global__ __launch_bounds__(512, 2)
void gemm_bt8(const u16* __restrict__ A, const u16* __restrict__ B,
              void* __restrict__ Cout, int M, int N, int K) {
    __shared__ __align__(16) u16 lds[65536];   // 128 KiB

    const int t    = threadIdx.x;              // 0..511
    const int lane = t & 63;
    const int wm   = (t >> 6) >> 2;            // 0..1
    const int wn   = (t >> 6) & 3;             // 0..3
    const int l15  = lane & 15;
    const int hi   = lane >> 4;                // 0..3
    const int l7   = lane & 7;

    // persistent mapping: 256 blocks = 8 XCD groups x 32 row slots
    const int nCols = N >> 8;
    const int TPB   = nCols >> 3;              // tiles per block
    const int xcd   = blockIdx.x & 7;
    const int slot  = blockIdx.x >> 3;
    const long rowA = (long)slot * 256;        // constant per block
    long rowB = (long)xcd * TPB * 256;

    // ---- staging sources (pre-swizzled global addresses, R1-verbatim) ----
    const int pl0 = t >> 3;                               // 0..63
    const int slotcol = ((t & 7) ^ (pl0 & 7)) * 8;
    const u16* Asrc[2][2];
    const u16* Bsrc[2][2];
#pragma unroll
    for (int h = 0; h < 2; h++) {
        Asrc[h][0] = A + (rowA + h * 64 + pl0) * (long)K + slotcol;
        Asrc[h][1] = A + (rowA + 128 + h * 64 + pl0) * (long)K + slotcol;
    }
    auto SET_B = [&](long rB) {
#pragma unroll
        for (int h = 0; h < 2; h++) {
            int nb = (pl0 >> 5) * 64 + h * 32 + (pl0 & 31);
            Bsrc[h][0] = B + (rB + nb) * (long)K + slotcol;
            Bsrc[h][1] = Bsrc[h][0] + 128 * (long)K;
        }
    };
    SET_B(rowB);
    const int t8 = t * 8;

    auto STAGE_A = [&](int bufo, int h, int kk) {
        u16* d = lds + bufo + h * 8192 + t8;
        async_copy16(Asrc[h][0] + kk, d);
        async_copy16(Asrc[h][1] + kk, d + 4096);
    };
    auto STAGE_B = [&](int bufo, int h, int kk) {
        u16* d = lds + bufo + 16384 + h * 8192 + t8;
        async_copy16(Bsrc[h][0] + kk, d);
        async_copy16(Bsrc[h][1] + kk, d + 4096);
    };

    // ---- fragment read offsets (u16 units, R1-verbatim) ----
    const int aBase = wm * 4096 + l15 * 64;
    const int bBase = 16384 + wn * 2048 + l15 * 64;
    const int sOff0 = (hi ^ l7) * 8;            // ks=0
    const int sOff1 = ((4 + hi) ^ l7) * 8;      // ks=1

    bf16x8 af[4][2], ba[2][2], bb[2][2];
    f32x4 acc[8][4] = {};

    auto LOAD_A2 = [&](int bufo, int Mq, int mb) {   // af[mb], af[mb+1]
        const u16* p = lds + bufo + Mq * 8192 + aBase + mb * 1024;
        af[mb][0]     = *(const bf16x8*)(p + sOff0);
        af[mb][1]     = *(const bf16x8*)(p + sOff1);
        af[mb + 1][0] = *(const bf16x8*)(p + 1024 + sOff0);
        af[mb + 1][1] = *(const bf16x8*)(p + 1024 + sOff1);
    };
    auto LOAD_B = [&](bf16x8 (&bg)[2][2], int bufo, int Nq) {
        const u16* p = lds + bufo + Nq * 8192 + bBase;
        bg[0][0] = *(const bf16x8*)(p + sOff0);
        bg[0][1] = *(const bf16x8*)(p + sOff1);
        bg[1][0] = *(const bf16x8*)(p + 1024 + sOff0);
        bg[1][1] = *(const bf16x8*)(p + 1024 + sOff1);
    };
    auto MFMA_H = [&](int Mq, int Nq, int mb, bf16x8 (&bg)[2][2]) {
        __builtin_amdgcn_s_setprio(1);
#pragma unroll
        for (int ks = 0; ks < 2; ks++)
#pragma unroll
            for (int m = mb; m < mb + 2; m++)
#pragma unroll
                for (int n = 0; n < 2; n++)
                    acc[Mq * 4 + m][Nq * 2 + n] =
                        __builtin_amdgcn_mfma_f32_16x16x32_bf16(
                            af[m][ks], bg[n][ks], acc[Mq * 4 + m][Nq * 2 + n],
                            0, 0, 0);
        __builtin_amdgcn_s_setprio(0);
    };

#define BAR()   __builtin_amdgcn_s_barrier()
#define SB()    __builtin_amdgcn_sched_barrier(0)
#define LGKM(n) do { asm volatile("s_waitcnt lgkmcnt(" #n ")" ::: "memory"); \
                     __builtin_amdgcn_sched_barrier(0); } while (0)
#define VM(n)   asm volatile("s_waitcnt vmcnt(" #n ")" ::: "memory")

    // one K-tile = 4 phases, 1 barrier each, 1 DMA sync (VM(0)@ph4-start);
    // compute from BC, stage next tile (all 4 regions, ph1/ph2) -> BN
#define TILE(BC, BN, KK)                                                     \
    /*ph1 Q(M0N0)*/                                                          \
    LOAD_B(ba, BC, 0); LOAD_A2(BC, 0, 0); SB(); LOAD_A2(BC, 0, 2);           \
    STAGE_A(BN, 0, KK); STAGE_B(BN, 0, KK);                                  \
    LGKM(4); MFMA_H(0, 0, 0, ba); LGKM(0); MFMA_H(0, 0, 2, ba); BAR();       \
    /*ph2 Q(M0N1)*/                                                          \
    LOAD_B(bb, BC, 1);                                                       \
    STAGE_B(BN, 1, KK); STAGE_A(BN, 1, KK);                                  \
    LGKM(0); MFMA_H(0, 1, 0, bb); MFMA_H(0, 1, 2, bb); BAR();                \
    /*ph3 Q(M1N1)*/                                                          \
    LOAD_A2(BC, 1, 0); SB(); LOAD_A2(BC, 1, 2);                              \
    LGKM(4); MFMA_H(1, 1, 0, bb); LGKM(0); MFMA_H(1, 1, 2, bb); BAR();       \
    /*ph4 Q(M1N0)*/                                                          \
    VM(0);                                                                   \
    MFMA_H(1, 0, 0, ba); MFMA_H(1, 0, 2, ba); BAR();

    // ---- prologue: stage ALL of tile0 -> buf0 (once) ----
    STAGE_A(0, 0, 0);  STAGE_B(0, 0, 0);
    STAGE_A(0, 1, 0);  STAGE_B(0, 1, 0);
    asm volatile("s_waitcnt vmcnt(0)" ::: "memory");
    BAR();

    const int NT = K >> 6;                     // K/64 tiles, even, >= 4
#pragma unroll 1
    for (int j = 0; j < TPB; j++) {
        const long rowBc = rowB;               // epilogue column base
#pragma unroll 1
        for (int i = 0; i < NT - 2; i += 2) {
            TILE(0, 32768, (i + 1) << 6);
            TILE(32768, 0, (i + 2) << 6);
        }
        TILE(0, 32768, (NT - 1) << 6);
        // last K-tile's stage = next output tile's prologue (k=0); for the
        // final tile it restages k=0 junk (valid memory, never read)
        if (j + 1 < TPB) { rowB += 256; SET_B(rowB); }
        TILE(32768, 0, 0);

        // epilogue: 16x16 C/D layout col=lane&15, row=(lane>>4)*4+r.
        // buf0 for the next tile is already staged+VM(0)+BAR'd; stores are
        // fire-and-forget and overlap the next K-loop's ph1.
        const long crowBase = rowA + wm * 128 + hi * 4;
        const long ccolBase = rowBc + wn * 64 + l15;
#pragma unroll
        for (int mi = 0; mi < 8; mi++) {
#pragma unroll
            for (int nj = 0; nj < 4; nj++) {
                long base = (crowBase + mi * 16) * N + ccolBase + nj * 16;
#pragma unroll
                for (int r = 0; r < 4; r++) {
                    float v = acc[mi][nj][r];
                    long idx = base + (long)r * N;
                    if (BF16_OUT) ((u16*)Cout)[idx] = f2bf(v);
                    else          ((float*)Cout)[idx] = v;
                }
            }
        }
        if (j + 1 < TPB) {
#pragma unroll
            for (int mi = 0; mi < 8; mi++)
#pragma unroll
                for (int nj = 0; nj < 4; nj++)
#pragma unroll
                    for (int r = 0; r < 4; r++)
                        acc[mi][nj][r] = 0.0f;
        }
    }
    // safety drain before LDS dealloc (queue should already be empty)
    asm volatile("s_waitcnt vmcnt(0) lgkmcnt(0)" ::: "memory");

#undef TILE
#undef VM
#undef LGKM
#undef SB
#undef BAR
}

// ---------------------------------------------------------------------------
// Fused Bx-product + depthwise causal conv(L=3) + C-gate, 4 rows/block.
// BCx: (8192, 6144) bf16 rows = [B(0:2048) | C(2048:4096) | x(4096:6144)]
// y[s,h] = C[s,h] * ( w[h,0]*Bx[s-2,h] + w[h,1]*Bx[s-1,h] + w[h,2]*Bx[s,h] )
// batch boundary: s resets every 4096 rows; 4096%4==0 so boundaries align
// to block starts — a tap row is valid iff it is in the block's batch.
// ---------------------------------------------------------------------------
union U16x8 { uint4 v; u16 u[8]; };

__global__ __launch_bounds__(256)
void conv_fuse(const u16* __restrict__ BCx, const float* __restrict__ cw,
               u16* __restrict__ y) {
    const int r0 = blockIdx.x * 4;         // 2048 blocks
    const int h0 = threadIdx.x * 8;        // 256*8 = 2048
    const int batch = r0 >> 12;

    U16x8 Bv[6], Xv[6], Cv[4];
#pragma unroll
    for (int ii = 0; ii < 6; ii++) {
        int g = r0 - 2 + ii;
        if (g >= 0 && (g >> 12) == batch) {
            const u16* rp = BCx + (long)g * 6144;
            Bv[ii].v = *(const uint4*)(rp + h0);
            Xv[ii].v = *(const uint4*)(rp + 4096 + h0);
        } else {
            Bv[ii].v = make_uint4(0, 0, 0, 0);
            Xv[ii].v = make_uint4(0, 0, 0, 0);
        }
    }
#pragma unroll
    for (int jj = 0; jj < 4; jj++)
        Cv[jj].v = *(const uint4*)(BCx + (long)(r0 + jj) * 6144 + 2048 + h0);

    float bx[6][8];
#pragma unroll
    for (int ii = 0; ii < 6; ii++)
#pragma unroll
        for (int i = 0; i < 8; i++)
            bx[ii][i] = bf2f(Bv[ii].u[i]) * bf2f(Xv[ii].u[i]);

    float w0[8], w1[8], w2[8];
#pragma unroll
    for (int i = 0; i < 8; i++) {
        int h = h0 + i;
        w0[i] = cw[h * 3];     // tap s-2
        w1[i] = cw[h * 3 + 1]; // tap s-1
        w2[i] = cw[h * 3 + 2]; // tap s
    }

#pragma unroll
    for (int jj = 0; jj < 4; jj++) {
        U16x8 o;
#pragma unroll
        for (int i = 0; i < 8; i++) {
            float v = w2[i] * bx[jj + 2][i] + w1[i] * bx[jj + 1][i]
                    + w0[i] * bx[jj][i];
            o.u[i] = f2bf(v * bf2f(Cv[jj].u[i]));
        }
        *(uint4*)(y + (long)(r0 + jj) * 2048 + h0) = o.v;
    }
}

// ---------------------------------------------------------------------------
extern "C" void kernel_launch(void* const* d_in, const int* in_sizes, int n_in,
                              void* d_out, int out_size, void* d_ws, size_t ws_size,
                              hipStream_t stream) {
    const float* hs   = (const float*)d_in[0];   // (2,4096,2048)
    const float* Win  = (const float*)d_in[1];   // (6144,2048)
    const float* cw   = (const float*)d_in[2];   // (2048,1,3)
    const float* Wout = (const float*)d_in[3];   // (2048,2048)
    float* out = (float*)d_out;                  // (2,4096,2048) fp32

    char* ws = (char*)d_ws;
    u16* hsb   = (u16*)(ws);                     //  33,554,432 B
    u16* Winb  = (u16*)(ws +  33554432);         //  25,165,824 B
    u16* Woutb = (u16*)(ws +  58720256);         //   8,388,608 B
    u16* bcx   = (u16*)(ws +  67108864);         // 100,663,296 B
    u16* yb    = (u16*)(ws + 167772160);         //  33,554,432 B  (end 201,326,592)

    cvt_all<<<4096, 256, 0, stream>>>(hs, Win, Wout, hsb, Winb, Woutb);

    // BCx = hs @ Win^T : M=8192, N=6144, K=2048  (persistent, 256 blocks x 3 tiles)
    gemm_bt8<true ><<<256, 512, 0, stream>>>(hsb, Winb, bcx, 8192, 6144, 2048);

    conv_fuse<<<2048, 256, 0, stream>>>(bcx, cw, yb);

    // out = y @ Wout^T : M=8192, N=2048, K=2048  (persistent, 256 blocks x 1 tile)
    gemm_bt8<false><<<256, 512, 0, stream>>>(yb, Woutb, out, 8192, 2048, 2048);
}

// Round 9
// 427.825 us; speedup vs baseline: 1.0406x; 1.0406x over previous
//
#include <hip/hip_runtime.h>
#include <hip/hip_bf16.h>

typedef unsigned short u16;
typedef __attribute__((ext_vector_type(8))) short bf16x8;    // 8 bf16 in 4 VGPRs
typedef __attribute__((ext_vector_type(4))) float f32x4;

static __device__ __forceinline__ u16 f2bf(float f) {
    unsigned u = __float_as_uint(f);
    unsigned r = (u + 0x7fffu + ((u >> 16) & 1u)) >> 16;   // RNE
    return (u16)r;
}
static __device__ __forceinline__ float bf2f(u16 u) {
    return __uint_as_float(((unsigned)u) << 16);
}

static __device__ __forceinline__ void async_copy16(const void* gptr, void* lptr) {
    __builtin_amdgcn_global_load_lds(
        (const __attribute__((address_space(1))) void*)gptr,
        (__attribute__((address_space(3))) void*)lptr, 16, 0, 0);
}

// ---------------------------------------------------------------------------
// fp32 -> bf16 for all three inputs, grid-stride (4096 blocks x 8 iters).
// Unit = float4. hs: 4,194,304 units; Win: 3,145,728; Wout: 1,048,576.
// ---------------------------------------------------------------------------
__global__ __launch_bounds__(256)
void cvt_all(const float* __restrict__ a, const float* __restrict__ b,
             const float* __restrict__ c,
             u16* __restrict__ oa, u16* __restrict__ ob, u16* __restrict__ oc) {
#pragma unroll
    for (int it = 0; it < 8; it++) {
        long li = ((long)it << 20) + (long)blockIdx.x * 256 + threadIdx.x;
        const float* src; u16* dst; long u;
        if (li < 4194304)      { src = a; dst = oa; u = li; }
        else if (li < 7340032) { src = b; dst = ob; u = li - 4194304; }
        else                   { src = c; dst = oc; u = li - 7340032; }
        long i = u * 4;
        float4 f = *(const float4*)(src + i);
        u16 o[4] = { f2bf(f.x), f2bf(f.y), f2bf(f.z), f2bf(f.w) };
        *(uint2*)(dst + i) = *(const uint2*)o;
    }
}

// ---------------------------------------------------------------------------
// C[m,n] = sum_k A[m,k] * B[n,k]   (row-major, K contiguous — "BT" gemm)
//
// 256x256 tile, BK=64, 512 threads = 8 waves (2M x 4N), wave tile 128x64 as
// 8x4 frags of mfma_f32_16x16x32_bf16 (16-row fragment reads = measured ZERO
// bank conflicts; 32-row variants measured 1.9e7). Grid-dispatched (R8's
// persistent mapping ballooned FETCH 181->425MB; reverted).
//
// R9: m201-EXACT phase discipline (never run before: R1 added vmcnt(10)
// every phase; R6/R7 dropped the 2-barrier split that setprio needs).
// Iter = 2 K-tiles (buf0, buf1), 8 phases; phase = quadrant x K64 = 16 MFMA:
//   [ds_reads (this phase's frags) | 1 region staged (2 copies)]
//   BAR; lgkmcnt(0); setprio(1) 16xMFMA setprio(0); [VM(6) @ph4/ph8]; BAR
// Reads/phase: ph1 af+ba(12) ph2 bb(4) ph3 af(8) ph4 0 | ph5-8 same.
// Stage slots: ph1 A1(t2i+1,buf1) ph2-5 A0,B0,B1,A1(t2i+2,buf0)
//              ph6-8 A0,B0,B1(t2i+3,buf1).
// FIFO audit: queue 14 at ph4-end -> VM(6) retires {prev ph6-8 (6) + ph1 A1}
//   = buf1 tile complete before ph5 reads; queue 14 at ph8-end -> retires
//   {ph2-5 (8)} = buf0 tile complete before next ph1. WAR: every stage >= 3
//   barriers after its region's last read-drain (lgkmcnt(0) pre-MFMA).
// Prologue: tile0 (4 regions) + tile1 A0,B0,B1 (3 regions); VM(6) -> tile0
//   landed, tile1's 6 copies in flight (retired by iter0's ph4 VM(6)).
//
// LDS (2 dbufs x 32768 u16): A-Mq at Mq*8192, B-Nq at 16384+Nq*8192;
// 16B slot s = kc ^ (rowslot&7). Swizzle pre-applied on the GLOBAL source
// (global_load_lds needs linear lane*16B dests); reads un-swizzle with the
// same XOR. (R1-verbatim zero-conflict geometry.)
// M,N mult of 256, K mult of 128, K>=256, gridDim.x mult of 8.
// ---------------------------------------------------------------------------
template<bool BF16_OUT>
__global__ __launch_bounds__(512, 2)
void gemm_bt8(const u16* __restrict__ A, const u16* __restrict__ B,
              void* __restrict__ Cout, int M, int N, int K) {
    __shared__ __align__(16) u16 lds[65536];   // 128 KiB

    const int t    = threadIdx.x;              // 0..511
    const int lane = t & 63;
    const int wm   = (t >> 6) >> 2;            // 0..1
    const int wn   = (t >> 6) & 3;             // 0..3
    const int l15  = lane & 15;
    const int hi   = lane >> 4;                // 0..3
    const int l7   = lane & 7;

    // XCD-aware panel remap (bijective since gridDim.x % 8 == 0)
    const int id   = blockIdx.y * gridDim.x + blockIdx.x;
    const int cpx  = gridDim.x >> 3;
    const int bx   = (id & 7) * cpx + ((id >> 3) % cpx);
    const int by   = (id >> 3) / cpx;
    const long rowA = (long)by * 256;
    const long rowB = (long)bx * 256;

    // ---- staging sources (pre-swizzled global addresses, R1-verbatim) ----
    const int pl0 = t >> 3;                               // 0..63
    const int slotcol = ((t & 7) ^ (pl0 & 7)) * 8;
    const u16* Asrc[2][2]; const u16* Bsrc[2][2];
#pragma unroll
    for (int h = 0; h < 2; h++) {
        Asrc[h][0] = A + (rowA + h * 64 + pl0) * (long)K + slotcol;
        Asrc[h][1] = A + (rowA + 128 + h * 64 + pl0) * (long)K + slotcol;
        int nB0 = (pl0 >> 5) * 64 + h * 32 + (pl0 & 31);
        Bsrc[h][0] = B + (rowB + nB0) * (long)K + slotcol;
        Bsrc[h][1] = Bsrc[h][0] + 128 * (long)K;
    }
    const int t8 = t * 8;

    auto STAGE_A = [&](int bufo, int h, int kk) {
        u16* d = lds + bufo + h * 8192 + t8;
        async_copy16(Asrc[h][0] + kk, d);
        async_copy16(Asrc[h][1] + kk, d + 4096);
    };
    auto STAGE_B = [&](int bufo, int h, int kk) {
        u16* d = lds + bufo + 16384 + h * 8192 + t8;
        async_copy16(Bsrc[h][0] + kk, d);
        async_copy16(Bsrc[h][1] + kk, d + 4096);
    };

    // ---- fragment read offsets (u16 units, R1-verbatim) ----
    const int aBase = wm * 4096 + l15 * 64;
    const int bBase = 16384 + wn * 2048 + l15 * 64;
    const int sOff0 = (hi ^ l7) * 8;            // ks=0
    const int sOff1 = ((4 + hi) ^ l7) * 8;      // ks=1

    bf16x8 af[4][2], ba[2][2], bb[2][2];
    f32x4 acc[8][4] = {};

    auto LOAD_A4 = [&](int bufo, int Mq) {      // 8 reads -> af
        const u16* p = lds + bufo + Mq * 8192 + aBase;
#pragma unroll
        for (int m = 0; m < 4; m++) {
            af[m][0] = *(const bf16x8*)(p + m * 1024 + sOff0);
            af[m][1] = *(const bf16x8*)(p + m * 1024 + sOff1);
        }
    };
    auto LOAD_B = [&](bf16x8 (&bg)[2][2], int bufo, int Nq) {  // 4 reads
        const u16* p = lds + bufo + Nq * 8192 + bBase;
        bg[0][0] = *(const bf16x8*)(p + sOff0);
        bg[0][1] = *(const bf16x8*)(p + sOff1);
        bg[1][0] = *(const bf16x8*)(p + 1024 + sOff0);
        bg[1][1] = *(const bf16x8*)(p + 1024 + sOff1);
    };
    auto MFMA_Q = [&](int Mq, int Nq, bf16x8 (&bg)[2][2]) {    // 16 MFMA
        __builtin_amdgcn_s_setprio(1);
#pragma unroll
        for (int ks = 0; ks < 2; ks++)
#pragma unroll
            for (int m = 0; m < 4; m++)
#pragma unroll
                for (int n = 0; n < 2; n++)
                    acc[Mq * 4 + m][Nq * 2 + n] =
                        __builtin_amdgcn_mfma_f32_16x16x32_bf16(
                            af[m][ks], bg[n][ks], acc[Mq * 4 + m][Nq * 2 + n],
                            0, 0, 0);
        __builtin_amdgcn_s_setprio(0);
    };

#define BAR()   __builtin_amdgcn_s_barrier()
#define LGKMZ() do { asm volatile("s_waitcnt lgkmcnt(0)" ::: "memory");      \
                     __builtin_amdgcn_sched_barrier(0); } while (0)
#define VM6()   asm volatile("s_waitcnt vmcnt(6)" ::: "memory")

    // ---- prologue: tile0 (all) + tile1 (A0,B0,B1) ----
    STAGE_A(0, 0, 0);      STAGE_A(0, 1, 0);
    STAGE_B(0, 0, 0);      STAGE_B(0, 1, 0);
    STAGE_A(32768, 0, 64); STAGE_B(32768, 0, 64); STAGE_B(32768, 1, 64);
    VM6();                                  // tile0's 8 copies landed
    BAR();

    const int NT = K >> 6;                     // K/64 tiles, even, >=4
    const int NI = NT >> 1;
#pragma unroll 1
    for (int i = 0; i < NI; i++) {
        const int kk1 = ((i << 1) + 1) << 6;                 // always < K
        int kk2 = ((i << 1) + 2) << 6; if (kk2 >= K) kk2 = 0; // tail junk,
        int kk3 = ((i << 1) + 3) << 6; if (kk3 >= K) kk3 = 0; //  never read
        // ph1: Q(T,M0N0); reads af,ba; stage A1(tile 2i+1 -> buf1)
        LOAD_A4(0, 0); LOAD_B(ba, 0, 0);
        STAGE_A(32768, 1, kk1);
        BAR(); LGKMZ(); MFMA_Q(0, 0, ba); BAR();
        // ph2: Q(T,M0N1); reads bb; stage A0(tile 2i+2 -> buf0)
        LOAD_B(bb, 0, 1);
        STAGE_A(0, 0, kk2);
        BAR(); LGKMZ(); MFMA_Q(0, 1, bb); BAR();
        // ph3: Q(T,M1N1); reads af; stage B0' -> buf0
        LOAD_A4(0, 1);
        STAGE_B(0, 0, kk2);
        BAR(); LGKMZ(); MFMA_Q(1, 1, bb); BAR();
        // ph4: Q(T,M1N0); no reads; stage B1' -> buf0; VM(6)
        STAGE_B(0, 1, kk2);
        BAR(); LGKMZ(); MFMA_Q(1, 0, ba); VM6(); BAR();
        // ph5: Q(T+1,M0N0); reads af,ba (buf1); stage A1' -> buf0
        LOAD_A4(32768, 0); LOAD_B(ba, 32768, 0);
        STAGE_A(0, 1, kk2);
        BAR(); LGKMZ(); MFMA_Q(0, 0, ba); BAR();
        // ph6: Q(T+1,M0N1); reads bb; stage A0''(tile 2i+3 -> buf1)
        LOAD_B(bb, 32768, 1);
        STAGE_A(32768, 0, kk3);
        BAR(); LGKMZ(); MFMA_Q(0, 1, bb); BAR();
        // ph7: Q(T+1,M1N1); reads af; stage B0'' -> buf1
        LOAD_A4(32768, 1);
        STAGE_B(32768, 0, kk3);
        BAR(); LGKMZ(); MFMA_Q(1, 1, bb); BAR();
        // ph8: Q(T+1,M1N0); no reads; stage B1'' -> buf1; VM(6)
        STAGE_B(32768, 1, kk3);
        BAR(); LGKMZ(); MFMA_Q(1, 0, ba); VM6(); BAR();
    }
    // drain in-flight LDS-targeted loads / reads before LDS dealloc
    asm volatile("s_waitcnt vmcnt(0) lgkmcnt(0)" ::: "memory");

#undef BAR
#undef LGKMZ
#undef VM6

    // ---- epilogue: 16x16 C/D layout col=lane&15, row=(lane>>4)*4+r ----
    const long crowBase = rowA + wm * 128 + hi * 4;
    const long ccolBase = rowB + wn * 64 + l15;
#pragma unroll
    for (int mi = 0; mi < 8; mi++) {
#pragma unroll
        for (int nj = 0; nj < 4; nj++) {
            long base = (crowBase + mi * 16) * N + ccolBase + nj * 16;
#pragma unroll
            for (int r = 0; r < 4; r++) {
                float v = acc[mi][nj][r];
                long idx = base + (long)r * N;
                if (BF16_OUT) ((u16*)Cout)[idx] = f2bf(v);
                else          ((float*)Cout)[idx] = v;
            }
        }
    }
}

// ---------------------------------------------------------------------------
// Fused Bx-product + depthwise causal conv(L=3) + C-gate, 4 rows/block.
// BCx: (8192, 6144) bf16 rows = [B(0:2048) | C(2048:4096) | x(4096:6144)]
// y[s,h] = C[s,h] * ( w[h,0]*Bx[s-2,h] + w[h,1]*Bx[s-1,h] + w[h,2]*Bx[s,h] )
// batch boundary: s resets every 4096 rows; 4096%4==0 so boundaries align
// to block starts — a tap row is valid iff it is in the block's batch.
// ---------------------------------------------------------------------------
union U16x8 { uint4 v; u16 u[8]; };

__global__ __launch_bounds__(256)
void conv_fuse(const u16* __restrict__ BCx, const float* __restrict__ cw,
               u16* __restrict__ y) {
    const int r0 = blockIdx.x * 4;         // 2048 blocks
    const int h0 = threadIdx.x * 8;        // 256*8 = 2048
    const int batch = r0 >> 12;

    U16x8 Bv[6], Xv[6], Cv[4];
#pragma unroll
    for (int ii = 0; ii < 6; ii++) {
        int g = r0 - 2 + ii;
        if (g >= 0 && (g >> 12) == batch) {
            const u16* rp = BCx + (long)g * 6144;
            Bv[ii].v = *(const uint4*)(rp + h0);
            Xv[ii].v = *(const uint4*)(rp + 4096 + h0);
        } else {
            Bv[ii].v = make_uint4(0, 0, 0, 0);
            Xv[ii].v = make_uint4(0, 0, 0, 0);
        }
    }
#pragma unroll
    for (int jj = 0; jj < 4; jj++)
        Cv[jj].v = *(const uint4*)(BCx + (long)(r0 + jj) * 6144 + 2048 + h0);

    float bx[6][8];
#pragma unroll
    for (int ii = 0; ii < 6; ii++)
#pragma unroll
        for (int i = 0; i < 8; i++)
            bx[ii][i] = bf2f(Bv[ii].u[i]) * bf2f(Xv[ii].u[i]);

    float w0[8], w1[8], w2[8];
#pragma unroll
    for (int i = 0; i < 8; i++) {
        int h = h0 + i;
        w0[i] = cw[h * 3];     // tap s-2
        w1[i] = cw[h * 3 + 1]; // tap s-1
        w2[i] = cw[h * 3 + 2]; // tap s
    }

#pragma unroll
    for (int jj = 0; jj < 4; jj++) {
        U16x8 o;
#pragma unroll
        for (int i = 0; i < 8; i++) {
            float v = w2[i] * bx[jj + 2][i] + w1[i] * bx[jj + 1][i]
                    + w0[i] * bx[jj][i];
            o.u[i] = f2bf(v * bf2f(Cv[jj].u[i]));
        }
        *(uint4*)(y + (long)(r0 + jj) * 2048 + h0) = o.v;
    }
}

// ---------------------------------------------------------------------------
extern "C" void kernel_launch(void* const* d_in, const int* in_sizes, int n_in,
                              void* d_out, int out_size, void* d_ws, size_t ws_size,
                              hipStream_t stream) {
    const float* hs   = (const float*)d_in[0];   // (2,4096,2048)
    const float* Win  = (const float*)d_in[1];   // (6144,2048)
    const float* cw   = (const float*)d_in[2];   // (2048,1,3)
    const float* Wout = (const float*)d_in[3];   // (2048,2048)
    float* out = (float*)d_out;                  // (2,4096,2048) fp32

    char* ws = (char*)d_ws;
    u16* hsb   = (u16*)(ws);                     //  33,554,432 B
    u16* Winb  = (u16*)(ws +  33554432);         //  25,165,824 B
    u16* Woutb = (u16*)(ws +  58720256);         //   8,388,608 B
    u16* bcx   = (u16*)(ws +  67108864);         // 100,663,296 B
    u16* yb    = (u16*)(ws + 167772160);         //  33,554,432 B  (end 201,326,592)

    cvt_all<<<4096, 256, 0, stream>>>(hs, Win, Wout, hsb, Winb, Woutb);

    // BCx = hs @ Win^T : M=8192, N=6144, K=2048  (grid 24x32 = 768 blocks)
    gemm_bt8<true ><<<dim3(24, 32), 512, 0, stream>>>(hsb, Winb, bcx, 8192, 6144, 2048);

    conv_fuse<<<2048, 256, 0, stream>>>(bcx, cw, yb);

    // out = y @ Wout^T : M=8192, N=2048, K=2048  (grid 8x32 = 256 blocks)
    gemm_bt8<false><<<dim3(8, 32), 512, 0, stream>>>(yb, Woutb, out, 8192, 2048, 2048);
}